// Round 11
// baseline (99.231 us; speedup 1.0000x reference)
//
#include <hip/hip_runtime.h>
#include <stdint.h>

#define BB 4
#define CC 64
#define HH 192
#define WW 192
#define HWN (HH*WW)            // 36864
#define KH 4
#define KW 16
#define PW (WW/KW)             // 12
#define MP ((HH/KH)*(WW/KW))   // 576
#define MITER (MP/64)          // 9
#define NCHUNK (HWN/256)       // 144 n-chunks for colsum
#define SCALE_W 65536.0f
#define INV_SCALE (1.0f/65536.0f)

typedef _Float16 half8 __attribute__((ext_vector_type(8)));
typedef _Float16 half4 __attribute__((ext_vector_type(4)));
typedef float floatx4 __attribute__((ext_vector_type(4)));

// async global->LDS, 16B per lane; LDS dest = uniform base + lane*16 (HW rule)
static __device__ __forceinline__ void gload16(const void* g, void* l) {
  __builtin_amdgcn_global_load_lds((const __attribute__((address_space(1))) void*)g,
                                   (__attribute__((address_space(3))) void*)l, 16, 0, 0);
}
#define WAITCNT_VM(N) asm volatile("s_waitcnt vmcnt(" #N ")" ::: "memory")
#define WAITCNT_LGKM0 asm volatile("s_waitcnt lgkmcnt(0)" ::: "memory")

// kptF fragment order (GEMM1 B-operand, cols permuted m=l15*4+mf):
//   chunk = (mi*4+mf)*2+ks per batch; f16 idx = chunk*512 + lane*8 + e
//   value = Kp[b][m=mi*64+(lane&15)*4+mf][c=ks*32+(lane>>4)*8+e]
// wqF fragment order (GEMM2 A-operand):
//   chunk = (mi*4+cf)*2+ks ; value = W'[b][c=cf*16+(lane&15)][m=mi*64+ks*32+(lane>>4)*8+e]

// ---------------- pooling: kptF (f16 frag-order) and Vp (f32, [b][c][m]) ---
__global__ __launch_bounds__(256) void pool_kernel(
    const float* __restrict__ Kin, const float* __restrict__ Vin,
    _Float16* __restrict__ kptF, float* __restrict__ vp) {
  int t = blockIdx.x * 256 + threadIdx.x;
  const int total = BB * CC * MP;
  bool isV = t >= total;
  int idx = isV ? t - total : t;
  int m = idx % MP;
  int c = (idx / MP) % CC;
  int b = idx / (MP * CC);
  int mh = m / PW, mw = m % PW;
  const float* src = (isV ? Vin : Kin) + (((b * CC + c) * HH + mh * KH) * WW + mw * KW);
  float s = 0.f;
#pragma unroll
  for (int r = 0; r < KH; ++r) {
    const float4* row = (const float4*)(src + r * WW);
#pragma unroll
    for (int j = 0; j < KW / 4; ++j) {
      float4 v = row[j];
      s += v.x + v.y + v.z + v.w;
    }
  }
  s *= (1.0f / (KH * KW));
  if (isV) {
    vp[(b * CC + c) * MP + m] = s;
  } else {
    int mi = m >> 6, mloc = m & 63, l15 = mloc >> 2, mf = mloc & 3;
    int ks = c >> 5, lhi = (c >> 3) & 3, e = c & 7;
    int lane = lhi * 16 + l15;
    kptF[(((((b * MITER + mi) * 4 + mf) * 2 + ks)) * 64 + lane) * 8 + e] = (_Float16)s;
  }
}

// ---------------- pass A1: partial colsum, fixed-m waves -------------------
// Block = 9 waves; wave wv OWNS m-tile mi=wv for the whole kernel and loops
// over 8 n-subtiles (256 n per block). B-fragments loop-invariant (loaded
// once); exp-sums accumulate in 4 per-lane scalars; the shfl reduce + store
// run ONCE per wave. No LDS, no barriers, no atomics.
// part[b][nc][m] lives in d_out scratch (dead until attn overwrites).
__global__ __launch_bounds__(576) void colsum_kernel(
    const float* __restrict__ Q, const _Float16* __restrict__ kptF,
    float* __restrict__ part) {
  int b = blockIdx.y;
  int n0 = blockIdx.x * 256;
  int tid = threadIdx.x;
  int wv = tid / 64;            // 0..8 == mi
  int lane = tid & 63;
  int l15 = lane & 15, lhi = lane >> 4;

  // loop-invariant B fragments for m-tile wv (coalesced 1KB chunks)
  const _Float16* kb = kptF + b * MITER * 8 * 512;
  half8 bfr[4][2];
#pragma unroll
  for (int mf = 0; mf < 4; ++mf)
#pragma unroll
    for (int ks = 0; ks < 2; ++ks)
      bfr[mf][ks] = *(const half8*)(kb + ((wv * 4 + mf) * 2 + ks) * 512 + lane * 8);

  const float* Qb = Q + b * CC * HWN;
  floatx4 zero = {0.f, 0.f, 0.f, 0.f};
  float s0 = 0.f, s1 = 0.f, s2 = 0.f, s3 = 0.f;

#pragma unroll
  for (int it = 0; it < 8; ++it) {
    int nr = n0 + it * 32 + l15;
    half8 af[2][2];
#pragma unroll
    for (int nf = 0; nf < 2; ++nf)
#pragma unroll
      for (int ks = 0; ks < 2; ++ks)
#pragma unroll
        for (int e = 0; e < 8; ++e)
          af[nf][ks][e] = (_Float16)Qb[(ks * 32 + lhi * 8 + e) * HWN + nr + nf * 16];

    floatx4 sacc[2][4];
#pragma unroll
    for (int nf = 0; nf < 2; ++nf)
#pragma unroll
      for (int mf = 0; mf < 4; ++mf) sacc[nf][mf] = zero;
    __builtin_amdgcn_s_setprio(1);
#pragma unroll
    for (int ks = 0; ks < 2; ++ks)
#pragma unroll
      for (int nf = 0; nf < 2; ++nf)
#pragma unroll
        for (int mf = 0; mf < 4; ++mf)
          sacc[nf][mf] = __builtin_amdgcn_mfma_f32_16x16x32_f16(
              af[nf][ks], bfr[mf][ks], sacc[nf][mf], 0, 0, 0);
    __builtin_amdgcn_s_setprio(0);

#pragma unroll
    for (int nf = 0; nf < 2; ++nf)
#pragma unroll
      for (int r = 0; r < 4; ++r) {
        s0 += __expf(sacc[nf][0][r]);
        s1 += __expf(sacc[nf][1][r]);
        s2 += __expf(sacc[nf][2][r]);
        s3 += __expf(sacc[nf][3][r]);
      }
  }

  // one reduce per wave: sum across lhi groups, then coalesced partial store
  s0 += __shfl_xor(s0, 16); s0 += __shfl_xor(s0, 32);
  s1 += __shfl_xor(s1, 16); s1 += __shfl_xor(s1, 32);
  s2 += __shfl_xor(s2, 16); s2 += __shfl_xor(s2, 32);
  s3 += __shfl_xor(s3, 16); s3 += __shfl_xor(s3, 32);
  if (lane < 16) {
    float* p = part + (b * NCHUNK + blockIdx.x) * MP + wv * 64 + l15 * 4;
    p[0] = s0; p[1] = s1; p[2] = s2; p[3] = s3;
  }
}

// ---------------- pass A2: colsum[b][m] = sum_nc part[b][nc][m] ------------
__global__ __launch_bounds__(256) void colsum_reduce_kernel(
    const float* __restrict__ part, float* __restrict__ colsum) {
  int t = blockIdx.x * 256 + threadIdx.x;  // 0..2303
  int m = t % MP;
  int b = t / MP;
  const float* p = part + b * NCHUNK * MP + m;
  float a0 = 0.f, a1 = 0.f, a2 = 0.f, a3 = 0.f;
#pragma unroll 4
  for (int nc = 0; nc < NCHUNK; nc += 4) {
    a0 += p[(nc + 0) * MP];
    a1 += p[(nc + 1) * MP];
    a2 += p[(nc + 2) * MP];
    a3 += p[(nc + 3) * MP];
  }
  colsum[t] = (a0 + a1) + (a2 + a3);
}

// ---------------- W' = Vp/colsum * 2^16 (f16, frag-order) ------------------
__global__ __launch_bounds__(256) void wprep_kernel(
    const float* __restrict__ vp, const float* __restrict__ colsum,
    _Float16* __restrict__ wqF) {
  int t = blockIdx.x * 256 + threadIdx.x;
  int m = t % MP;
  int c = (t / MP) % CC;
  int b = t / (CC * MP);
  float w = vp[t] / colsum[b * MP + m] * SCALE_W;
  int cf = c >> 4, l15 = c & 15;
  int mi = m >> 6, mloc = m & 63;
  int ks = mloc >> 5, lhi = (mloc >> 3) & 3, e = mloc & 7;
  int lane = lhi * 16 + l15;
  wqF[((((b * MITER + mi) * 4 + cf) * 2 + ks) * 64 + lane) * 8 + e] = (_Float16)w;
}

// ---------------- pass B: attn (unchanged from R10) ------------------------
__global__ __launch_bounds__(256, 2) void attn_main_kernel(
    const float* __restrict__ Q, const _Float16* __restrict__ kptF,
    const _Float16* __restrict__ wqF, float* __restrict__ out) {
  __shared__ char lds[3 * 16384 + 4 * 4096];  // 64KB exactly
  char* stg = lds;
  int b = blockIdx.y;
  int n0 = blockIdx.x * 128;
  int tid = threadIdx.x;
  int wv = tid >> 6;
  int lane = tid & 63;
  int l15 = lane & 15, lhi = lane >> 4;
  char* eb = lds + 49152 + wv * 4096;

  const _Float16* kb = kptF + b * MITER * 8 * 512;
  const _Float16* wb = wqF + b * MITER * 8 * 512;

#define STAGE_A(tt, ss)                                                        \
  {                                                                            \
    int q0_ = wv * 4;                                                          \
    _Pragma("unroll") for (int j_ = 0; j_ < 4; ++j_) {                         \
      int q_ = q0_ + j_;                                                       \
      const _Float16* sp_ = (q_ < 8 ? kb + (tt) * 4096 + q_ * 512              \
                                    : wb + (tt) * 4096 + (q_ - 8) * 512) +     \
                            lane * 8;                                          \
      gload16(sp_, stg + (ss) * 16384 + q_ * 1024);                            \
    }                                                                          \
  }

  STAGE_A(0, 0);
  STAGE_A(1, 1);

  const float* Qb = Q + b * CC * HWN;
  int nrow = n0 + wv * 32 + l15;
  half8 afrag[2][2];
#pragma unroll
  for (int nf = 0; nf < 2; ++nf)
#pragma unroll
    for (int ks = 0; ks < 2; ++ks)
#pragma unroll
      for (int e = 0; e < 8; ++e)
        afrag[nf][ks][e] = (_Float16)Qb[(ks * 32 + lhi * 8 + e) * HWN + nrow + nf * 16];

  floatx4 zero = {0.f, 0.f, 0.f, 0.f};
  floatx4 oacc[4][2];
#pragma unroll
  for (int cf = 0; cf < 4; ++cf)
#pragma unroll
    for (int nf = 0; nf < 2; ++nf) oacc[cf][nf] = zero;

  WAITCNT_VM(4);
  __builtin_amdgcn_sched_barrier(0);
  __builtin_amdgcn_s_barrier();

#pragma unroll
  for (int mi = 0; mi < MITER; ++mi) {
    const int sc = mi % 3;
    const int spv = (mi + 2) % 3;

    if (mi >= 1) {
      if (mi <= 7) { WAITCNT_VM(4); } else { WAITCNT_VM(0); }
      __builtin_amdgcn_sched_barrier(0);
      __builtin_amdgcn_s_barrier();
    }

    half8 bfr[4][2];
#pragma unroll
    for (int mf = 0; mf < 4; ++mf)
#pragma unroll
      for (int ks = 0; ks < 2; ++ks)
        bfr[mf][ks] = *(const half8*)(stg + sc * 16384 + (mf * 2 + ks) * 1024 + lane * 16);
    half8 wfr[4][2];
    half8 ef[2][2];
    if (mi >= 1) {
#pragma unroll
      for (int cf = 0; cf < 4; ++cf)
#pragma unroll
        for (int ks = 0; ks < 2; ++ks)
          wfr[cf][ks] = *(const half8*)(stg + spv * 16384 + 8192 + (cf * 2 + ks) * 1024 + lane * 16);
#pragma unroll
      for (int nf = 0; nf < 2; ++nf)
#pragma unroll
        for (int ks = 0; ks < 2; ++ks) {
          int nl = nf * 16 + l15;
          int slot = (ks * 4 + lhi) ^ (nl & 7);
          ef[nf][ks] = *(const half8*)(eb + nl * 128 + (slot << 4));
        }
    }

    WAITCNT_LGKM0;
    __builtin_amdgcn_sched_barrier(0);
    __builtin_amdgcn_s_barrier();

    if (mi + 2 < MITER) STAGE_A(mi + 2, spv);

    floatx4 sacc[2][4];
#pragma unroll
    for (int nf = 0; nf < 2; ++nf)
#pragma unroll
      for (int mf = 0; mf < 4; ++mf) sacc[nf][mf] = zero;
    __builtin_amdgcn_s_setprio(1);
#pragma unroll
    for (int ks = 0; ks < 2; ++ks)
#pragma unroll
      for (int nf = 0; nf < 2; ++nf)
#pragma unroll
        for (int mf = 0; mf < 4; ++mf)
          sacc[nf][mf] = __builtin_amdgcn_mfma_f32_16x16x32_f16(
              afrag[nf][ks], bfr[mf][ks], sacc[nf][mf], 0, 0, 0);
    if (mi >= 1) {
#pragma unroll
      for (int ks = 0; ks < 2; ++ks)
#pragma unroll
        for (int cf = 0; cf < 4; ++cf)
#pragma unroll
          for (int nf = 0; nf < 2; ++nf)
            oacc[cf][nf] = __builtin_amdgcn_mfma_f32_16x16x32_f16(
                wfr[cf][ks], ef[nf][ks], oacc[cf][nf], 0, 0, 0);
    }
    __builtin_amdgcn_s_setprio(0);

#pragma unroll
    for (int nf = 0; nf < 2; ++nf)
#pragma unroll
      for (int r = 0; r < 4; ++r) {
        int nl = nf * 16 + lhi * 4 + r;
        half4 h;
#pragma unroll
        for (int mf = 0; mf < 4; ++mf) h[mf] = (_Float16)__expf(sacc[nf][mf][r]);
        int byte = nl * 128 + ((((l15 >> 1) ^ (nl & 7))) << 4) + ((l15 & 1) << 3);
        *(half4*)(eb + byte) = h;
      }
  }

  {
    half8 wfr[4][2];
#pragma unroll
    for (int cf = 0; cf < 4; ++cf)
#pragma unroll
      for (int ks = 0; ks < 2; ++ks)
        wfr[cf][ks] = *(const half8*)(stg + 2 * 16384 + 8192 + (cf * 2 + ks) * 1024 + lane * 16);
    half8 ef[2][2];
#pragma unroll
    for (int nf = 0; nf < 2; ++nf)
#pragma unroll
      for (int ks = 0; ks < 2; ++ks) {
        int nl = nf * 16 + l15;
        int slot = (ks * 4 + lhi) ^ (nl & 7);
        ef[nf][ks] = *(const half8*)(eb + nl * 128 + (slot << 4));
      }
    __builtin_amdgcn_s_setprio(1);
#pragma unroll
    for (int ks = 0; ks < 2; ++ks)
#pragma unroll
      for (int cf = 0; cf < 4; ++cf)
#pragma unroll
        for (int nf = 0; nf < 2; ++nf)
          oacc[cf][nf] = __builtin_amdgcn_mfma_f32_16x16x32_f16(
              wfr[cf][ks], ef[nf][ks], oacc[cf][nf], 0, 0, 0);
    __builtin_amdgcn_s_setprio(0);
  }

  float* ob = out + b * CC * HWN;
#pragma unroll
  for (int cf = 0; cf < 4; ++cf)
#pragma unroll
    for (int nf = 0; nf < 2; ++nf)
#pragma unroll
      for (int r = 0; r < 4; ++r) {
        int c = cf * 16 + lhi * 4 + r;
        int n = n0 + wv * 32 + nf * 16 + l15;
        ob[c * HWN + n] = oacc[cf][nf][r] * INV_SCALE;
      }
}

extern "C" void kernel_launch(void* const* d_in, const int* in_sizes, int n_in,
                              void* d_out, int out_size, void* d_ws, size_t ws_size,
                              hipStream_t stream) {
  const float* K = (const float*)d_in[0];
  const float* Q = (const float*)d_in[1];
  const float* V = (const float*)d_in[2];
  float* out = (float*)d_out;
  char* ws = (char*)d_ws;
  _Float16* kptF  = (_Float16*)(ws);                          // 294912 B
  float*    vp    = (float*)(ws + 294912);                    // 589824 B
  _Float16* wqF   = (_Float16*)(ws + 294912 + 589824);        // 294912 B
  float*    colsum = (float*)(ws + 294912 + 589824 + 294912); // 9216 B
  float*    part  = out;  // 1.33 MB scratch inside d_out; dead before attn

  pool_kernel<<<(2 * BB * CC * MP) / 256, 256, 0, stream>>>(K, V, kptF, vp);
  colsum_kernel<<<dim3(NCHUNK, BB), 576, 0, stream>>>(Q, kptF, part);
  colsum_reduce_kernel<<<(BB * MP) / 256, 256, 0, stream>>>(part, colsum);
  wprep_kernel<<<(BB * CC * MP) / 256, 256, 0, stream>>>(vp, colsum, wqF);
  attn_main_kernel<<<dim3(HWN / 128, BB), 256, 0, stream>>>(Q, kptF, wqF, out);
}

// Round 12
// 88.372 us; speedup vs baseline: 1.1229x; 1.1229x over previous
//
#include <hip/hip_runtime.h>
#include <stdint.h>

#define BB 4
#define CC 64
#define HH 192
#define WW 192
#define HWN (HH*WW)            // 36864
#define KH 4
#define KW 16
#define PW (WW/KW)             // 12
#define MP ((HH/KH)*(WW/KW))   // 576
#define MITER (MP/64)          // 9
#define NCHUNK (HWN/256)       // 144 n-chunks (256 rows each) for colsum
#define NBTOT (HWN/32)         // 1152 32-row n-blocks per batch
#define SCALE_W 65536.0f
#define INV_SCALE (1.0f/65536.0f)

typedef _Float16 half8 __attribute__((ext_vector_type(8)));
typedef _Float16 half4 __attribute__((ext_vector_type(4)));
typedef float floatx4 __attribute__((ext_vector_type(4)));

// async global->LDS, 16B per lane; LDS dest = uniform base + lane*16 (HW rule)
static __device__ __forceinline__ void gload16(const void* g, void* l) {
  __builtin_amdgcn_global_load_lds((const __attribute__((address_space(1))) void*)g,
                                   (__attribute__((address_space(3))) void*)l, 16, 0, 0);
}
#define WAITCNT_VM(N) asm volatile("s_waitcnt vmcnt(" #N ")" ::: "memory")
#define WAITCNT_LGKM0 asm volatile("s_waitcnt lgkmcnt(0)" ::: "memory")

// kptF fragment order (GEMM1 B-operand, cols permuted m=l15*4+mf):
//   chunk = (mi*4+mf)*2+ks per batch; f16 idx = chunk*512 + lane*8 + e
//   value = Kp[b][m=mi*64+(lane&15)*4+mf][c=ks*32+(lane>>4)*8+e]
// wqF fragment order (GEMM2 A-operand):
//   chunk = (mi*4+cf)*2+ks ; value = W'[b][c=cf*16+(lane&15)][m=mi*64+ks*32+(lane>>4)*8+e]
// qF fragment order (GEMM1 A-operand, f16):
//   chunk = (b*NBTOT+nb)*4 + ks*2 + nf ; f16 idx = chunk*512 + lane*8 + e
//   value = Q[b][c=ks*32+(lane>>4)*8+e][n=nb*32+nf*16+(lane&15)]

// ---------------- pooling: kptF (f16 frag-order) and Vp (f32, [b][c][m]) ---
__global__ __launch_bounds__(256) void pool_kernel(
    const float* __restrict__ Kin, const float* __restrict__ Vin,
    _Float16* __restrict__ kptF, float* __restrict__ vp) {
  int t = blockIdx.x * 256 + threadIdx.x;
  const int total = BB * CC * MP;
  bool isV = t >= total;
  int idx = isV ? t - total : t;
  int m = idx % MP;
  int c = (idx / MP) % CC;
  int b = idx / (MP * CC);
  int mh = m / PW, mw = m % PW;
  const float* src = (isV ? Vin : Kin) + (((b * CC + c) * HH + mh * KH) * WW + mw * KW);
  float s = 0.f;
#pragma unroll
  for (int r = 0; r < KH; ++r) {
    const float4* row = (const float4*)(src + r * WW);
#pragma unroll
    for (int j = 0; j < KW / 4; ++j) {
      float4 v = row[j];
      s += v.x + v.y + v.z + v.w;
    }
  }
  s *= (1.0f / (KH * KW));
  if (isV) {
    vp[(b * CC + c) * MP + m] = s;
  } else {
    int mi = m >> 6, mloc = m & 63, l15 = mloc >> 2, mf = mloc & 3;
    int ks = c >> 5, lhi = (c >> 3) & 3, e = c & 7;
    int lane = lhi * 16 + l15;
    kptF[(((((b * MITER + mi) * 4 + mf) * 2 + ks)) * 64 + lane) * 8 + e] = (_Float16)s;
  }
}

// ---------------- Q -> f16 fragment order (one-time streaming transform) ---
__global__ __launch_bounds__(256) void qprep_kernel(
    const float* __restrict__ Q, _Float16* __restrict__ qF) {
  int t = blockIdx.x * 256 + threadIdx.x;
  int chunk = t >> 6;            // wave-uniform
  int lane = t & 63;
  int nf = chunk & 1;
  int ks = (chunk >> 1) & 1;
  int idx = chunk >> 2;          // b*NBTOT + nb
  int nb = idx % NBTOT;
  int b = idx / NBTOT;
  int c0 = ks * 32 + (lane >> 4) * 8;
  int n = nb * 32 + nf * 16 + (lane & 15);
  const float* Qb = Q + (b * CC + c0) * HWN + n;
  half8 h;
#pragma unroll
  for (int e = 0; e < 8; ++e) h[e] = (_Float16)Qb[e * HWN];
  *(half8*)(qF + chunk * 512 + lane * 8) = h;
}

// ---------------- pass A1: partial colsum (qF path) ------------------------
// Bag-of-independent-waves: 512-thr blocks, 8 autonomous waves. Unit u =
// bid*8+wv -> (mi, b, nc): wave owns m-tile mi, loops 8 n-blocks of chunk nc.
// B fragments loop-invariant; A fragments = 4 contiguous 16B/lane loads from
// qF (no gather, no cvt); exp-sums in 4 scalars; one shfl reduce at the end.
// No LDS, no barriers. VGPR <=128 -> 16 waves/CU -> 2 blocks/CU.
__global__ __launch_bounds__(512) void colsum_qf_kernel(
    const _Float16* __restrict__ qF, const _Float16* __restrict__ kptF,
    float* __restrict__ part) {
  int tid = threadIdx.x;
  int lane = tid & 63;
  int l15 = lane & 15;
  int u = blockIdx.x * 8 + (tid >> 6);   // 0..5183
  int mi = u % 9;
  int v = u / 9;
  int b = v / NCHUNK;
  int nc = v % NCHUNK;

  const _Float16* kb = kptF + b * MITER * 8 * 512;
  half8 bfr[4][2];
#pragma unroll
  for (int mf = 0; mf < 4; ++mf)
#pragma unroll
    for (int ks = 0; ks < 2; ++ks)
      bfr[mf][ks] = *(const half8*)(kb + ((mi * 4 + mf) * 2 + ks) * 512 + lane * 8);

  floatx4 zero = {0.f, 0.f, 0.f, 0.f};
  float s0 = 0.f, s1 = 0.f, s2 = 0.f, s3 = 0.f;

#pragma unroll
  for (int it = 0; it < 8; ++it) {
    int nb = nc * 8 + it;
    const _Float16* qc = qF + (size_t)((b * NBTOT + nb) * 4) * 512 + lane * 8;
    half8 af[2][2];
#pragma unroll
    for (int ks = 0; ks < 2; ++ks)
#pragma unroll
      for (int nf = 0; nf < 2; ++nf)
        af[nf][ks] = *(const half8*)(qc + (ks * 2 + nf) * 512);

    floatx4 sacc[2][4];
#pragma unroll
    for (int nf = 0; nf < 2; ++nf)
#pragma unroll
      for (int mf = 0; mf < 4; ++mf) sacc[nf][mf] = zero;
    __builtin_amdgcn_s_setprio(1);
#pragma unroll
    for (int ks = 0; ks < 2; ++ks)
#pragma unroll
      for (int nf = 0; nf < 2; ++nf)
#pragma unroll
        for (int mf = 0; mf < 4; ++mf)
          sacc[nf][mf] = __builtin_amdgcn_mfma_f32_16x16x32_f16(
              af[nf][ks], bfr[mf][ks], sacc[nf][mf], 0, 0, 0);
    __builtin_amdgcn_s_setprio(0);

#pragma unroll
    for (int nf = 0; nf < 2; ++nf)
#pragma unroll
      for (int r = 0; r < 4; ++r) {
        s0 += __expf(sacc[nf][0][r]);
        s1 += __expf(sacc[nf][1][r]);
        s2 += __expf(sacc[nf][2][r]);
        s3 += __expf(sacc[nf][3][r]);
      }
  }

  s0 += __shfl_xor(s0, 16); s0 += __shfl_xor(s0, 32);
  s1 += __shfl_xor(s1, 16); s1 += __shfl_xor(s1, 32);
  s2 += __shfl_xor(s2, 16); s2 += __shfl_xor(s2, 32);
  s3 += __shfl_xor(s3, 16); s3 += __shfl_xor(s3, 32);
  if (lane < 16) {
    float* p = part + (b * NCHUNK + nc) * MP + mi * 64 + l15 * 4;
    p[0] = s0; p[1] = s1; p[2] = s2; p[3] = s3;
  }
}

// ---------------- pass A1 fallback (R11, gather path) ----------------------
__global__ __launch_bounds__(576) void colsum_fb_kernel(
    const float* __restrict__ Q, const _Float16* __restrict__ kptF,
    float* __restrict__ part) {
  int b = blockIdx.y;
  int n0 = blockIdx.x * 256;
  int tid = threadIdx.x;
  int wv = tid / 64;
  int lane = tid & 63;
  int l15 = lane & 15, lhi = lane >> 4;

  const _Float16* kb = kptF + b * MITER * 8 * 512;
  half8 bfr[4][2];
#pragma unroll
  for (int mf = 0; mf < 4; ++mf)
#pragma unroll
    for (int ks = 0; ks < 2; ++ks)
      bfr[mf][ks] = *(const half8*)(kb + ((wv * 4 + mf) * 2 + ks) * 512 + lane * 8);

  const float* Qb = Q + b * CC * HWN;
  floatx4 zero = {0.f, 0.f, 0.f, 0.f};
  float s0 = 0.f, s1 = 0.f, s2 = 0.f, s3 = 0.f;

#pragma unroll
  for (int it = 0; it < 8; ++it) {
    int nr = n0 + it * 32 + l15;
    half8 af[2][2];
#pragma unroll
    for (int nf = 0; nf < 2; ++nf)
#pragma unroll
      for (int ks = 0; ks < 2; ++ks)
#pragma unroll
        for (int e = 0; e < 8; ++e)
          af[nf][ks][e] = (_Float16)Qb[(ks * 32 + lhi * 8 + e) * HWN + nr + nf * 16];

    floatx4 sacc[2][4];
#pragma unroll
    for (int nf = 0; nf < 2; ++nf)
#pragma unroll
      for (int mf = 0; mf < 4; ++mf) sacc[nf][mf] = zero;
    __builtin_amdgcn_s_setprio(1);
#pragma unroll
    for (int ks = 0; ks < 2; ++ks)
#pragma unroll
      for (int nf = 0; nf < 2; ++nf)
#pragma unroll
        for (int mf = 0; mf < 4; ++mf)
          sacc[nf][mf] = __builtin_amdgcn_mfma_f32_16x16x32_f16(
              af[nf][ks], bfr[mf][ks], sacc[nf][mf], 0, 0, 0);
    __builtin_amdgcn_s_setprio(0);

#pragma unroll
    for (int nf = 0; nf < 2; ++nf)
#pragma unroll
      for (int r = 0; r < 4; ++r) {
        s0 += __expf(sacc[nf][0][r]);
        s1 += __expf(sacc[nf][1][r]);
        s2 += __expf(sacc[nf][2][r]);
        s3 += __expf(sacc[nf][3][r]);
      }
  }

  s0 += __shfl_xor(s0, 16); s0 += __shfl_xor(s0, 32);
  s1 += __shfl_xor(s1, 16); s1 += __shfl_xor(s1, 32);
  s2 += __shfl_xor(s2, 16); s2 += __shfl_xor(s2, 32);
  s3 += __shfl_xor(s3, 16); s3 += __shfl_xor(s3, 32);
  if (lane < 16) {
    float* p = part + (b * NCHUNK + blockIdx.x) * MP + wv * 64 + l15 * 4;
    p[0] = s0; p[1] = s1; p[2] = s2; p[3] = s3;
  }
}

// ---------------- pass A2: colsum[b][m] = sum_nc part[b][nc][m] ------------
__global__ __launch_bounds__(256) void colsum_reduce_kernel(
    const float* __restrict__ part, float* __restrict__ colsum) {
  int t = blockIdx.x * 256 + threadIdx.x;  // 0..2303
  int m = t % MP;
  int b = t / MP;
  const float* p = part + b * NCHUNK * MP + m;
  float a0 = 0.f, a1 = 0.f, a2 = 0.f, a3 = 0.f;
#pragma unroll 4
  for (int nc = 0; nc < NCHUNK; nc += 4) {
    a0 += p[(nc + 0) * MP];
    a1 += p[(nc + 1) * MP];
    a2 += p[(nc + 2) * MP];
    a3 += p[(nc + 3) * MP];
  }
  colsum[t] = (a0 + a1) + (a2 + a3);
}

// ---------------- W' = Vp/colsum * 2^16 (f16, frag-order) ------------------
__global__ __launch_bounds__(256) void wprep_kernel(
    const float* __restrict__ vp, const float* __restrict__ colsum,
    _Float16* __restrict__ wqF) {
  int t = blockIdx.x * 256 + threadIdx.x;
  int m = t % MP;
  int c = (t / MP) % CC;
  int b = t / (CC * MP);
  float w = vp[t] / colsum[b * MP + m] * SCALE_W;
  int cf = c >> 4, l15 = c & 15;
  int mi = m >> 6, mloc = m & 63;
  int ks = mloc >> 5, lhi = (mloc >> 3) & 3, e = mloc & 7;
  int lane = lhi * 16 + l15;
  wqF[((((b * MITER + mi) * 4 + cf) * 2 + ks) * 64 + lane) * 8 + e] = (_Float16)w;
}

// ---------------- pass B: attn (unchanged from R10) ------------------------
__global__ __launch_bounds__(256, 2) void attn_main_kernel(
    const float* __restrict__ Q, const _Float16* __restrict__ kptF,
    const _Float16* __restrict__ wqF, float* __restrict__ out) {
  __shared__ char lds[3 * 16384 + 4 * 4096];  // 64KB exactly
  char* stg = lds;
  int b = blockIdx.y;
  int n0 = blockIdx.x * 128;
  int tid = threadIdx.x;
  int wv = tid >> 6;
  int lane = tid & 63;
  int l15 = lane & 15, lhi = lane >> 4;
  char* eb = lds + 49152 + wv * 4096;

  const _Float16* kb = kptF + b * MITER * 8 * 512;
  const _Float16* wb = wqF + b * MITER * 8 * 512;

#define STAGE_A(tt, ss)                                                        \
  {                                                                            \
    int q0_ = wv * 4;                                                          \
    _Pragma("unroll") for (int j_ = 0; j_ < 4; ++j_) {                         \
      int q_ = q0_ + j_;                                                       \
      const _Float16* sp_ = (q_ < 8 ? kb + (tt) * 4096 + q_ * 512              \
                                    : wb + (tt) * 4096 + (q_ - 8) * 512) +     \
                            lane * 8;                                          \
      gload16(sp_, stg + (ss) * 16384 + q_ * 1024);                            \
    }                                                                          \
  }

  STAGE_A(0, 0);
  STAGE_A(1, 1);

  const float* Qb = Q + b * CC * HWN;
  int nrow = n0 + wv * 32 + l15;
  half8 afrag[2][2];
#pragma unroll
  for (int nf = 0; nf < 2; ++nf)
#pragma unroll
    for (int ks = 0; ks < 2; ++ks)
#pragma unroll
      for (int e = 0; e < 8; ++e)
        afrag[nf][ks][e] = (_Float16)Qb[(ks * 32 + lhi * 8 + e) * HWN + nrow + nf * 16];

  floatx4 zero = {0.f, 0.f, 0.f, 0.f};
  floatx4 oacc[4][2];
#pragma unroll
  for (int cf = 0; cf < 4; ++cf)
#pragma unroll
    for (int nf = 0; nf < 2; ++nf) oacc[cf][nf] = zero;

  WAITCNT_VM(4);
  __builtin_amdgcn_sched_barrier(0);
  __builtin_amdgcn_s_barrier();

#pragma unroll
  for (int mi = 0; mi < MITER; ++mi) {
    const int sc = mi % 3;
    const int spv = (mi + 2) % 3;

    if (mi >= 1) {
      if (mi <= 7) { WAITCNT_VM(4); } else { WAITCNT_VM(0); }
      __builtin_amdgcn_sched_barrier(0);
      __builtin_amdgcn_s_barrier();
    }

    half8 bfr[4][2];
#pragma unroll
    for (int mf = 0; mf < 4; ++mf)
#pragma unroll
      for (int ks = 0; ks < 2; ++ks)
        bfr[mf][ks] = *(const half8*)(stg + sc * 16384 + (mf * 2 + ks) * 1024 + lane * 16);
    half8 wfr[4][2];
    half8 ef[2][2];
    if (mi >= 1) {
#pragma unroll
      for (int cf = 0; cf < 4; ++cf)
#pragma unroll
        for (int ks = 0; ks < 2; ++ks)
          wfr[cf][ks] = *(const half8*)(stg + spv * 16384 + 8192 + (cf * 2 + ks) * 1024 + lane * 16);
#pragma unroll
      for (int nf = 0; nf < 2; ++nf)
#pragma unroll
        for (int ks = 0; ks < 2; ++ks) {
          int nl = nf * 16 + l15;
          int slot = (ks * 4 + lhi) ^ (nl & 7);
          ef[nf][ks] = *(const half8*)(eb + nl * 128 + (slot << 4));
        }
    }

    WAITCNT_LGKM0;
    __builtin_amdgcn_sched_barrier(0);
    __builtin_amdgcn_s_barrier();

    if (mi + 2 < MITER) STAGE_A(mi + 2, spv);

    floatx4 sacc[2][4];
#pragma unroll
    for (int nf = 0; nf < 2; ++nf)
#pragma unroll
      for (int mf = 0; mf < 4; ++mf) sacc[nf][mf] = zero;
    __builtin_amdgcn_s_setprio(1);
#pragma unroll
    for (int ks = 0; ks < 2; ++ks)
#pragma unroll
      for (int nf = 0; nf < 2; ++nf)
#pragma unroll
        for (int mf = 0; mf < 4; ++mf)
          sacc[nf][mf] = __builtin_amdgcn_mfma_f32_16x16x32_f16(
              afrag[nf][ks], bfr[mf][ks], sacc[nf][mf], 0, 0, 0);
    if (mi >= 1) {
#pragma unroll
      for (int ks = 0; ks < 2; ++ks)
#pragma unroll
        for (int cf = 0; cf < 4; ++cf)
#pragma unroll
          for (int nf = 0; nf < 2; ++nf)
            oacc[cf][nf] = __builtin_amdgcn_mfma_f32_16x16x32_f16(
                wfr[cf][ks], ef[nf][ks], oacc[cf][nf], 0, 0, 0);
    }
    __builtin_amdgcn_s_setprio(0);

#pragma unroll
    for (int nf = 0; nf < 2; ++nf)
#pragma unroll
      for (int r = 0; r < 4; ++r) {
        int nl = nf * 16 + lhi * 4 + r;
        half4 h;
#pragma unroll
        for (int mf = 0; mf < 4; ++mf) h[mf] = (_Float16)__expf(sacc[nf][mf][r]);
        int byte = nl * 128 + ((((l15 >> 1) ^ (nl & 7))) << 4) + ((l15 & 1) << 3);
        *(half4*)(eb + byte) = h;
      }
  }

  {
    half8 wfr[4][2];
#pragma unroll
    for (int cf = 0; cf < 4; ++cf)
#pragma unroll
      for (int ks = 0; ks < 2; ++ks)
        wfr[cf][ks] = *(const half8*)(stg + 2 * 16384 + 8192 + (cf * 2 + ks) * 1024 + lane * 16);
    half8 ef[2][2];
#pragma unroll
    for (int nf = 0; nf < 2; ++nf)
#pragma unroll
      for (int ks = 0; ks < 2; ++ks) {
        int nl = nf * 16 + l15;
        int slot = (ks * 4 + lhi) ^ (nl & 7);
        ef[nf][ks] = *(const half8*)(eb + nl * 128 + (slot << 4));
      }
    __builtin_amdgcn_s_setprio(1);
#pragma unroll
    for (int ks = 0; ks < 2; ++ks)
#pragma unroll
      for (int cf = 0; cf < 4; ++cf)
#pragma unroll
        for (int nf = 0; nf < 2; ++nf)
          oacc[cf][nf] = __builtin_amdgcn_mfma_f32_16x16x32_f16(
              wfr[cf][ks], ef[nf][ks], oacc[cf][nf], 0, 0, 0);
    __builtin_amdgcn_s_setprio(0);
  }

  float* ob = out + b * CC * HWN;
#pragma unroll
  for (int cf = 0; cf < 4; ++cf)
#pragma unroll
    for (int nf = 0; nf < 2; ++nf)
#pragma unroll
      for (int r = 0; r < 4; ++r) {
        int c = cf * 16 + lhi * 4 + r;
        int n = n0 + wv * 32 + nf * 16 + l15;
        ob[c * HWN + n] = oacc[cf][nf][r] * INV_SCALE;
      }
}

extern "C" void kernel_launch(void* const* d_in, const int* in_sizes, int n_in,
                              void* d_out, int out_size, void* d_ws, size_t ws_size,
                              hipStream_t stream) {
  const float* K = (const float*)d_in[0];
  const float* Q = (const float*)d_in[1];
  const float* V = (const float*)d_in[2];
  float* out = (float*)d_out;
  char* ws = (char*)d_ws;
  _Float16* kptF  = (_Float16*)(ws);                          // 294912 B
  float*    vp    = (float*)(ws + 294912);                    // 589824 B
  _Float16* wqF   = (_Float16*)(ws + 294912 + 589824);        // 294912 B
  float*    colsum = (float*)(ws + 294912 + 589824 + 294912); // 9216 B
  const size_t QF_OFF = 1204224;                              // 256B-aligned
  const size_t QF_BYTES = (size_t)BB * NBTOT * 4 * 512 * 2;   // 18.87 MB
  _Float16* qF = (_Float16*)(ws + QF_OFF);
  float* part = out;  // 1.33 MB scratch inside d_out; dead before attn writes

  pool_kernel<<<(2 * BB * CC * MP) / 256, 256, 0, stream>>>(K, V, kptF, vp);
  if (ws_size >= QF_OFF + QF_BYTES) {
    qprep_kernel<<<(BB * NBTOT * 4 * 64) / 256, 256, 0, stream>>>(Q, qF);
    colsum_qf_kernel<<<(BB * NCHUNK * 9) / 8, 512, 0, stream>>>(qF, kptF, part);
  } else {
    colsum_fb_kernel<<<dim3(NCHUNK, BB), 576, 0, stream>>>(Q, kptF, part);
  }
  colsum_reduce_kernel<<<(BB * MP) / 256, 256, 0, stream>>>(part, colsum);
  wprep_kernel<<<(BB * CC * MP) / 256, 256, 0, stream>>>(vp, colsum, wqF);
  attn_main_kernel<<<dim3(HWN / 128, BB), 256, 0, stream>>>(Q, kptF, wqF, out);
}

// Round 13
// 85.548 us; speedup vs baseline: 1.1599x; 1.0330x over previous
//
#include <hip/hip_runtime.h>
#include <stdint.h>

#define BB 4
#define CC 64
#define HH 192
#define WW 192
#define HWN (HH*WW)            // 36864
#define KH 4
#define KW 16
#define PW (WW/KW)             // 12
#define MP ((HH/KH)*(WW/KW))   // 576
#define MITER (MP/64)          // 9
#define NCHUNK (HWN/256)       // 144 n-chunks (256 rows each) for colsum
#define NBTOT (HWN/32)         // 1152 32-row n-blocks per batch
#define SCALE_W 65536.0f
#define INV_SCALE (1.0f/65536.0f)

typedef _Float16 half8 __attribute__((ext_vector_type(8)));
typedef _Float16 half4 __attribute__((ext_vector_type(4)));
typedef float floatx4 __attribute__((ext_vector_type(4)));

// async global->LDS, 16B per lane; LDS dest = uniform base + lane*16 (HW rule)
static __device__ __forceinline__ void gload16(const void* g, void* l) {
  __builtin_amdgcn_global_load_lds((const __attribute__((address_space(1))) void*)g,
                                   (__attribute__((address_space(3))) void*)l, 16, 0, 0);
}
#define WAITCNT_VM(N) asm volatile("s_waitcnt vmcnt(" #N ")" ::: "memory")
#define WAITCNT_LGKM0 asm volatile("s_waitcnt lgkmcnt(0)" ::: "memory")

// kptF: chunk=(mi*4+mf)*2+ks; value = Kp[b][m=mi*64+(lane&15)*4+mf][c=ks*32+(lane>>4)*8+e]
// wqF:  chunk=(mi*4+cf)*2+ks; value = W'[b][c=cf*16+(lane&15)][m=mi*64+ks*32+(lane>>4)*8+e]
// qF:   chunk=(b*NBTOT+nb)*4+ks*2+nf; value = Q[b][c=ks*32+(lane>>4)*8+e][n=nb*32+nf*16+(lane&15)]

// ---------------- pooling: kptF (f16 frag-order) and Vp (f32, [b][c][m]) ---
__global__ __launch_bounds__(256) void pool_kernel(
    const float* __restrict__ Kin, const float* __restrict__ Vin,
    _Float16* __restrict__ kptF, float* __restrict__ vp) {
  int t = blockIdx.x * 256 + threadIdx.x;
  const int total = BB * CC * MP;
  bool isV = t >= total;
  int idx = isV ? t - total : t;
  int m = idx % MP;
  int c = (idx / MP) % CC;
  int b = idx / (MP * CC);
  int mh = m / PW, mw = m % PW;
  const float* src = (isV ? Vin : Kin) + (((b * CC + c) * HH + mh * KH) * WW + mw * KW);
  float s = 0.f;
#pragma unroll
  for (int r = 0; r < KH; ++r) {
    const float4* row = (const float4*)(src + r * WW);
#pragma unroll
    for (int j = 0; j < KW / 4; ++j) {
      float4 v = row[j];
      s += v.x + v.y + v.z + v.w;
    }
  }
  s *= (1.0f / (KH * KW));
  if (isV) {
    vp[(b * CC + c) * MP + m] = s;
  } else {
    int mi = m >> 6, mloc = m & 63, l15 = mloc >> 2, mf = mloc & 3;
    int ks = c >> 5, lhi = (c >> 3) & 3, e = c & 7;
    int lane = lhi * 16 + l15;
    kptF[(((((b * MITER + mi) * 4 + mf) * 2 + ks)) * 64 + lane) * 8 + e] = (_Float16)s;
  }
}

// ---------------- Q -> f16 fragment order (one-time streaming transform) ---
__global__ __launch_bounds__(256) void qprep_kernel(
    const float* __restrict__ Q, _Float16* __restrict__ qF) {
  int t = blockIdx.x * 256 + threadIdx.x;
  int chunk = t >> 6;            // wave-uniform
  int lane = t & 63;
  int nf = chunk & 1;
  int ks = (chunk >> 1) & 1;
  int idx = chunk >> 2;          // b*NBTOT + nb
  int nb = idx % NBTOT;
  int b = idx / NBTOT;
  int c0 = ks * 32 + (lane >> 4) * 8;
  int n = nb * 32 + nf * 16 + (lane & 15);
  const float* Qb = Q + (b * CC + c0) * HWN + n;
  half8 h;
#pragma unroll
  for (int e = 0; e < 8; ++e) h[e] = (_Float16)Qb[e * HWN];
  *(half8*)(qF + chunk * 512 + lane * 8) = h;
}

// ---------------- pass A1: partial colsum (qF path, unchanged R12) ---------
__global__ __launch_bounds__(512) void colsum_qf_kernel(
    const _Float16* __restrict__ qF, const _Float16* __restrict__ kptF,
    float* __restrict__ part) {
  int tid = threadIdx.x;
  int lane = tid & 63;
  int l15 = lane & 15;
  int u = blockIdx.x * 8 + (tid >> 6);   // 0..5183
  int mi = u % 9;
  int v = u / 9;
  int b = v / NCHUNK;
  int nc = v % NCHUNK;

  const _Float16* kb = kptF + b * MITER * 8 * 512;
  half8 bfr[4][2];
#pragma unroll
  for (int mf = 0; mf < 4; ++mf)
#pragma unroll
    for (int ks = 0; ks < 2; ++ks)
      bfr[mf][ks] = *(const half8*)(kb + ((mi * 4 + mf) * 2 + ks) * 512 + lane * 8);

  floatx4 zero = {0.f, 0.f, 0.f, 0.f};
  float s0 = 0.f, s1 = 0.f, s2 = 0.f, s3 = 0.f;

#pragma unroll
  for (int it = 0; it < 8; ++it) {
    int nb = nc * 8 + it;
    const _Float16* qc = qF + (size_t)((b * NBTOT + nb) * 4) * 512 + lane * 8;
    half8 af[2][2];
#pragma unroll
    for (int ks = 0; ks < 2; ++ks)
#pragma unroll
      for (int nf = 0; nf < 2; ++nf)
        af[nf][ks] = *(const half8*)(qc + (ks * 2 + nf) * 512);

    floatx4 sacc[2][4];
#pragma unroll
    for (int nf = 0; nf < 2; ++nf)
#pragma unroll
      for (int mf = 0; mf < 4; ++mf) sacc[nf][mf] = zero;
    __builtin_amdgcn_s_setprio(1);
#pragma unroll
    for (int ks = 0; ks < 2; ++ks)
#pragma unroll
      for (int nf = 0; nf < 2; ++nf)
#pragma unroll
        for (int mf = 0; mf < 4; ++mf)
          sacc[nf][mf] = __builtin_amdgcn_mfma_f32_16x16x32_f16(
              af[nf][ks], bfr[mf][ks], sacc[nf][mf], 0, 0, 0);
    __builtin_amdgcn_s_setprio(0);

#pragma unroll
    for (int nf = 0; nf < 2; ++nf)
#pragma unroll
      for (int r = 0; r < 4; ++r) {
        s0 += __expf(sacc[nf][0][r]);
        s1 += __expf(sacc[nf][1][r]);
        s2 += __expf(sacc[nf][2][r]);
        s3 += __expf(sacc[nf][3][r]);
      }
  }

  s0 += __shfl_xor(s0, 16); s0 += __shfl_xor(s0, 32);
  s1 += __shfl_xor(s1, 16); s1 += __shfl_xor(s1, 32);
  s2 += __shfl_xor(s2, 16); s2 += __shfl_xor(s2, 32);
  s3 += __shfl_xor(s3, 16); s3 += __shfl_xor(s3, 32);
  if (lane < 16) {
    float* p = part + (b * NCHUNK + nc) * MP + mi * 64 + l15 * 4;
    p[0] = s0; p[1] = s1; p[2] = s2; p[3] = s3;
  }
}

// ---------------- pass A1 fallback (gather path) ---------------------------
__global__ __launch_bounds__(576) void colsum_fb_kernel(
    const float* __restrict__ Q, const _Float16* __restrict__ kptF,
    float* __restrict__ part) {
  int b = blockIdx.y;
  int n0 = blockIdx.x * 256;
  int tid = threadIdx.x;
  int wv = tid / 64;
  int lane = tid & 63;
  int l15 = lane & 15, lhi = lane >> 4;

  const _Float16* kb = kptF + b * MITER * 8 * 512;
  half8 bfr[4][2];
#pragma unroll
  for (int mf = 0; mf < 4; ++mf)
#pragma unroll
    for (int ks = 0; ks < 2; ++ks)
      bfr[mf][ks] = *(const half8*)(kb + ((wv * 4 + mf) * 2 + ks) * 512 + lane * 8);

  const float* Qb = Q + b * CC * HWN;
  floatx4 zero = {0.f, 0.f, 0.f, 0.f};
  float s0 = 0.f, s1 = 0.f, s2 = 0.f, s3 = 0.f;

#pragma unroll
  for (int it = 0; it < 8; ++it) {
    int nr = n0 + it * 32 + l15;
    half8 af[2][2];
#pragma unroll
    for (int nf = 0; nf < 2; ++nf)
#pragma unroll
      for (int ks = 0; ks < 2; ++ks)
#pragma unroll
        for (int e = 0; e < 8; ++e)
          af[nf][ks][e] = (_Float16)Qb[(ks * 32 + lhi * 8 + e) * HWN + nr + nf * 16];

    floatx4 sacc[2][4];
#pragma unroll
    for (int nf = 0; nf < 2; ++nf)
#pragma unroll
      for (int mf = 0; mf < 4; ++mf) sacc[nf][mf] = zero;
    __builtin_amdgcn_s_setprio(1);
#pragma unroll
    for (int ks = 0; ks < 2; ++ks)
#pragma unroll
      for (int nf = 0; nf < 2; ++nf)
#pragma unroll
        for (int mf = 0; mf < 4; ++mf)
          sacc[nf][mf] = __builtin_amdgcn_mfma_f32_16x16x32_f16(
              af[nf][ks], bfr[mf][ks], sacc[nf][mf], 0, 0, 0);
    __builtin_amdgcn_s_setprio(0);

#pragma unroll
    for (int nf = 0; nf < 2; ++nf)
#pragma unroll
      for (int r = 0; r < 4; ++r) {
        s0 += __expf(sacc[nf][0][r]);
        s1 += __expf(sacc[nf][1][r]);
        s2 += __expf(sacc[nf][2][r]);
        s3 += __expf(sacc[nf][3][r]);
      }
  }

  s0 += __shfl_xor(s0, 16); s0 += __shfl_xor(s0, 32);
  s1 += __shfl_xor(s1, 16); s1 += __shfl_xor(s1, 32);
  s2 += __shfl_xor(s2, 16); s2 += __shfl_xor(s2, 32);
  s3 += __shfl_xor(s3, 16); s3 += __shfl_xor(s3, 32);
  if (lane < 16) {
    float* p = part + (b * NCHUNK + blockIdx.x) * MP + wv * 64 + l15 * 4;
    p[0] = s0; p[1] = s1; p[2] = s2; p[3] = s3;
  }
}

// ---------------- pass A2: colsum[b][m] = sum_nc part[b][nc][m] ------------
__global__ __launch_bounds__(256) void colsum_reduce_kernel(
    const float* __restrict__ part, float* __restrict__ colsum) {
  int t = blockIdx.x * 256 + threadIdx.x;  // 0..2303
  int m = t % MP;
  int b = t / MP;
  const float* p = part + b * NCHUNK * MP + m;
  float a0 = 0.f, a1 = 0.f, a2 = 0.f, a3 = 0.f;
#pragma unroll 4
  for (int nc = 0; nc < NCHUNK; nc += 4) {
    a0 += p[(nc + 0) * MP];
    a1 += p[(nc + 1) * MP];
    a2 += p[(nc + 2) * MP];
    a3 += p[(nc + 3) * MP];
  }
  colsum[t] = (a0 + a1) + (a2 + a3);
}

// ---------------- W' = Vp/colsum * 2^16 (f16, frag-order) ------------------
__global__ __launch_bounds__(256) void wprep_kernel(
    const float* __restrict__ vp, const float* __restrict__ colsum,
    _Float16* __restrict__ wqF) {
  int t = blockIdx.x * 256 + threadIdx.x;
  int m = t % MP;
  int c = (t / MP) % CC;
  int b = t / (CC * MP);
  float w = vp[t] / colsum[b * MP + m] * SCALE_W;
  int cf = c >> 4, l15 = c & 15;
  int mi = m >> 6, mloc = m & 63;
  int ks = mloc >> 5, lhi = (mloc >> 3) & 3, e = mloc & 7;
  int lane = lhi * 16 + l15;
  wqF[((((b * MITER + mi) * 4 + cf) * 2 + ks) * 64 + lane) * 8 + e] = (_Float16)w;
}

// ---------------- pass B (qF path): one barrier/body, 2-slot ring ----------
// 4 waves x 32 rows; afrag from qF (4 contiguous loads); GEMM1+exp+E-roundtrip
// +GEMM2 all in the SAME body so the tile is fully consumed per body ->
// 2-slot ring (32KB) + 4x4KB E = 48KB -> 3 blocks/CU (12 waves/CU).
__global__ __launch_bounds__(256) void attn_qf_kernel(
    const _Float16* __restrict__ qF, const _Float16* __restrict__ kptF,
    const _Float16* __restrict__ wqF, float* __restrict__ out) {
  __shared__ char lds[2 * 16384 + 4 * 4096];  // 48KB
  char* stg = lds;
  int b = blockIdx.y;
  int tid = threadIdx.x;
  int wv = tid >> 6;
  int lane = tid & 63;
  int l15 = lane & 15, lhi = lane >> 4;
  char* eb = lds + 32768 + wv * 4096;

  const _Float16* kb = kptF + b * MITER * 8 * 512;
  const _Float16* wb = wqF + b * MITER * 8 * 512;

  // stage tile tt -> slot ss: 16 chunks of 1KB (8 kpt + 8 wq), 4 per wave
#define STAGE_Q(tt, ss)                                                        \
  {                                                                            \
    int q0_ = wv * 4;                                                          \
    _Pragma("unroll") for (int j_ = 0; j_ < 4; ++j_) {                         \
      int q_ = q0_ + j_;                                                       \
      const _Float16* sp_ = (q_ < 8 ? kb + (tt) * 4096 + q_ * 512              \
                                    : wb + (tt) * 4096 + (q_ - 8) * 512) +     \
                            lane * 8;                                          \
      gload16(sp_, stg + (ss) * 16384 + q_ * 1024);                            \
    }                                                                          \
  }

  STAGE_Q(0, 0);

  // A fragments from qF: 4 contiguous 16B/lane loads (no gather, no cvt)
  int nb = blockIdx.x * 4 + wv;
  const _Float16* qc = qF + (size_t)((b * NBTOT + nb) * 4) * 512 + lane * 8;
  half8 afrag[2][2];
#pragma unroll
  for (int ks = 0; ks < 2; ++ks)
#pragma unroll
    for (int nf = 0; nf < 2; ++nf)
      afrag[nf][ks] = *(const half8*)(qc + (ks * 2 + nf) * 512);

  floatx4 zero = {0.f, 0.f, 0.f, 0.f};
  floatx4 oacc[4][2];
#pragma unroll
  for (int cf = 0; cf < 4; ++cf)
#pragma unroll
    for (int nf = 0; nf < 2; ++nf) oacc[cf][nf] = zero;

#pragma unroll
  for (int mi = 0; mi < MITER; ++mi) {
    const int sc = mi & 1;
    // body top: my ds reads drained, stage(mi) landed, everyone past last body
    WAITCNT_LGKM0;
    WAITCNT_VM(0);
    __builtin_amdgcn_sched_barrier(0);
    __builtin_amdgcn_s_barrier();
    if (mi + 1 < MITER) STAGE_Q(mi + 1, sc ^ 1);

    half8 bfr[4][2];
#pragma unroll
    for (int mf = 0; mf < 4; ++mf)
#pragma unroll
      for (int ks = 0; ks < 2; ++ks)
        bfr[mf][ks] = *(const half8*)(stg + sc * 16384 + (mf * 2 + ks) * 1024 + lane * 16);
    half8 wfr[4][2];
#pragma unroll
    for (int cf = 0; cf < 4; ++cf)
#pragma unroll
      for (int ks = 0; ks < 2; ++ks)
        wfr[cf][ks] = *(const half8*)(stg + sc * 16384 + 8192 + (cf * 2 + ks) * 1024 + lane * 16);

    // GEMM1(mi)
    floatx4 sacc[2][4];
#pragma unroll
    for (int nf = 0; nf < 2; ++nf)
#pragma unroll
      for (int mf = 0; mf < 4; ++mf) sacc[nf][mf] = zero;
    __builtin_amdgcn_s_setprio(1);
#pragma unroll
    for (int ks = 0; ks < 2; ++ks)
#pragma unroll
      for (int nf = 0; nf < 2; ++nf)
#pragma unroll
        for (int mf = 0; mf < 4; ++mf)
          sacc[nf][mf] = __builtin_amdgcn_mfma_f32_16x16x32_f16(
              afrag[nf][ks], bfr[mf][ks], sacc[nf][mf], 0, 0, 0);
    __builtin_amdgcn_s_setprio(0);

    // exp -> E (swizzled, per-wave). Same-wave LDS FIFO: later reads see this.
#pragma unroll
    for (int nf = 0; nf < 2; ++nf)
#pragma unroll
      for (int r = 0; r < 4; ++r) {
        int nl = nf * 16 + lhi * 4 + r;
        half4 h;
#pragma unroll
        for (int mf = 0; mf < 4; ++mf) h[mf] = (_Float16)__expf(sacc[nf][mf][r]);
        int byte = nl * 128 + ((((l15 >> 1) ^ (nl & 7))) << 4) + ((l15 & 1) << 3);
        *(half4*)(eb + byte) = h;
      }

    // E^T fragments + GEMM2(mi), same body
    half8 ef[2][2];
#pragma unroll
    for (int nf = 0; nf < 2; ++nf)
#pragma unroll
      for (int ks = 0; ks < 2; ++ks) {
        int nl = nf * 16 + l15;
        int slot = (ks * 4 + lhi) ^ (nl & 7);
        ef[nf][ks] = *(const half8*)(eb + nl * 128 + (slot << 4));
      }
    __builtin_amdgcn_s_setprio(1);
#pragma unroll
    for (int ks = 0; ks < 2; ++ks)
#pragma unroll
      for (int cf = 0; cf < 4; ++cf)
#pragma unroll
        for (int nf = 0; nf < 2; ++nf)
          oacc[cf][nf] = __builtin_amdgcn_mfma_f32_16x16x32_f16(
              wfr[cf][ks], ef[nf][ks], oacc[cf][nf], 0, 0, 0);
    __builtin_amdgcn_s_setprio(0);
  }

  float* ob = out + b * CC * HWN;
#pragma unroll
  for (int cf = 0; cf < 4; ++cf)
#pragma unroll
    for (int nf = 0; nf < 2; ++nf)
#pragma unroll
      for (int r = 0; r < 4; ++r) {
        int c = cf * 16 + lhi * 4 + r;
        int n = nb * 32 + nf * 16 + l15;
        ob[c * HWN + n] = oacc[cf][nf][r] * INV_SCALE;
      }
}

// ---------------- pass B fallback (R12 structure, Q-gather) ----------------
__global__ __launch_bounds__(256, 2) void attn_main_kernel(
    const float* __restrict__ Q, const _Float16* __restrict__ kptF,
    const _Float16* __restrict__ wqF, float* __restrict__ out) {
  __shared__ char lds[3 * 16384 + 4 * 4096];  // 64KB exactly
  char* stg = lds;
  int b = blockIdx.y;
  int n0 = blockIdx.x * 128;
  int tid = threadIdx.x;
  int wv = tid >> 6;
  int lane = tid & 63;
  int l15 = lane & 15, lhi = lane >> 4;
  char* eb = lds + 49152 + wv * 4096;

  const _Float16* kb = kptF + b * MITER * 8 * 512;
  const _Float16* wb = wqF + b * MITER * 8 * 512;

#define STAGE_A(tt, ss)                                                        \
  {                                                                            \
    int q0_ = wv * 4;                                                          \
    _Pragma("unroll") for (int j_ = 0; j_ < 4; ++j_) {                         \
      int q_ = q0_ + j_;                                                       \
      const _Float16* sp_ = (q_ < 8 ? kb + (tt) * 4096 + q_ * 512              \
                                    : wb + (tt) * 4096 + (q_ - 8) * 512) +     \
                            lane * 8;                                          \
      gload16(sp_, stg + (ss) * 16384 + q_ * 1024);                            \
    }                                                                          \
  }

  STAGE_A(0, 0);
  STAGE_A(1, 1);

  const float* Qb = Q + b * CC * HWN;
  int nrow = n0 + wv * 32 + l15;
  half8 afrag[2][2];
#pragma unroll
  for (int nf = 0; nf < 2; ++nf)
#pragma unroll
    for (int ks = 0; ks < 2; ++ks)
#pragma unroll
      for (int e = 0; e < 8; ++e)
        afrag[nf][ks][e] = (_Float16)Qb[(ks * 32 + lhi * 8 + e) * HWN + nrow + nf * 16];

  floatx4 zero = {0.f, 0.f, 0.f, 0.f};
  floatx4 oacc[4][2];
#pragma unroll
  for (int cf = 0; cf < 4; ++cf)
#pragma unroll
    for (int nf = 0; nf < 2; ++nf) oacc[cf][nf] = zero;

  WAITCNT_VM(4);
  __builtin_amdgcn_sched_barrier(0);
  __builtin_amdgcn_s_barrier();

#pragma unroll
  for (int mi = 0; mi < MITER; ++mi) {
    const int sc = mi % 3;
    const int spv = (mi + 2) % 3;

    if (mi >= 1) {
      if (mi <= 7) { WAITCNT_VM(4); } else { WAITCNT_VM(0); }
      __builtin_amdgcn_sched_barrier(0);
      __builtin_amdgcn_s_barrier();
    }

    half8 bfr[4][2];
#pragma unroll
    for (int mf = 0; mf < 4; ++mf)
#pragma unroll
      for (int ks = 0; ks < 2; ++ks)
        bfr[mf][ks] = *(const half8*)(stg + sc * 16384 + (mf * 2 + ks) * 1024 + lane * 16);
    half8 wfr[4][2];
    half8 ef[2][2];
    if (mi >= 1) {
#pragma unroll
      for (int cf = 0; cf < 4; ++cf)
#pragma unroll
        for (int ks = 0; ks < 2; ++ks)
          wfr[cf][ks] = *(const half8*)(stg + spv * 16384 + 8192 + (cf * 2 + ks) * 1024 + lane * 16);
#pragma unroll
      for (int nf = 0; nf < 2; ++nf)
#pragma unroll
        for (int ks = 0; ks < 2; ++ks) {
          int nl = nf * 16 + l15;
          int slot = (ks * 4 + lhi) ^ (nl & 7);
          ef[nf][ks] = *(const half8*)(eb + nl * 128 + (slot << 4));
        }
    }

    WAITCNT_LGKM0;
    __builtin_amdgcn_sched_barrier(0);
    __builtin_amdgcn_s_barrier();

    if (mi + 2 < MITER) STAGE_A(mi + 2, spv);

    floatx4 sacc[2][4];
#pragma unroll
    for (int nf = 0; nf < 2; ++nf)
#pragma unroll
      for (int mf = 0; mf < 4; ++mf) sacc[nf][mf] = zero;
    __builtin_amdgcn_s_setprio(1);
#pragma unroll
    for (int ks = 0; ks < 2; ++ks)
#pragma unroll
      for (int nf = 0; nf < 2; ++nf)
#pragma unroll
        for (int mf = 0; mf < 4; ++mf)
          sacc[nf][mf] = __builtin_amdgcn_mfma_f32_16x16x32_f16(
              afrag[nf][ks], bfr[mf][ks], sacc[nf][mf], 0, 0, 0);
    if (mi >= 1) {
#pragma unroll
      for (int ks = 0; ks < 2; ++ks)
#pragma unroll
        for (int cf = 0; cf < 4; ++cf)
#pragma unroll
          for (int nf = 0; nf < 2; ++nf)
            oacc[cf][nf] = __builtin_amdgcn_mfma_f32_16x16x32_f16(
                wfr[cf][ks], ef[nf][ks], oacc[cf][nf], 0, 0, 0);
    }
    __builtin_amdgcn_s_setprio(0);

#pragma unroll
    for (int nf = 0; nf < 2; ++nf)
#pragma unroll
      for (int r = 0; r < 4; ++r) {
        int nl = nf * 16 + lhi * 4 + r;
        half4 h;
#pragma unroll
        for (int mf = 0; mf < 4; ++mf) h[mf] = (_Float16)__expf(sacc[nf][mf][r]);
        int byte = nl * 128 + ((((l15 >> 1) ^ (nl & 7))) << 4) + ((l15 & 1) << 3);
        *(half4*)(eb + byte) = h;
      }
  }

  {
    half8 wfr[4][2];
#pragma unroll
    for (int cf = 0; cf < 4; ++cf)
#pragma unroll
      for (int ks = 0; ks < 2; ++ks)
        wfr[cf][ks] = *(const half8*)(stg + 2 * 16384 + 8192 + (cf * 2 + ks) * 1024 + lane * 16);
    half8 ef[2][2];
#pragma unroll
    for (int nf = 0; nf < 2; ++nf)
#pragma unroll
      for (int ks = 0; ks < 2; ++ks) {
        int nl = nf * 16 + l15;
        int slot = (ks * 4 + lhi) ^ (nl & 7);
        ef[nf][ks] = *(const half8*)(eb + nl * 128 + (slot << 4));
      }
    __builtin_amdgcn_s_setprio(1);
#pragma unroll
    for (int ks = 0; ks < 2; ++ks)
#pragma unroll
      for (int cf = 0; cf < 4; ++cf)
#pragma unroll
        for (int nf = 0; nf < 2; ++nf)
          oacc[cf][nf] = __builtin_amdgcn_mfma_f32_16x16x32_f16(
              wfr[cf][ks], ef[nf][ks], oacc[cf][nf], 0, 0, 0);
    __builtin_amdgcn_s_setprio(0);
  }

  float* ob = out + b * CC * HWN;
#pragma unroll
  for (int cf = 0; cf < 4; ++cf)
#pragma unroll
    for (int nf = 0; nf < 2; ++nf)
#pragma unroll
      for (int r = 0; r < 4; ++r) {
        int c = cf * 16 + lhi * 4 + r;
        int n = n0 + wv * 32 + nf * 16 + l15;
        ob[c * HWN + n] = oacc[cf][nf][r] * INV_SCALE;
      }
}

extern "C" void kernel_launch(void* const* d_in, const int* in_sizes, int n_in,
                              void* d_out, int out_size, void* d_ws, size_t ws_size,
                              hipStream_t stream) {
  const float* K = (const float*)d_in[0];
  const float* Q = (const float*)d_in[1];
  const float* V = (const float*)d_in[2];
  float* out = (float*)d_out;
  char* ws = (char*)d_ws;
  _Float16* kptF  = (_Float16*)(ws);                          // 294912 B
  float*    vp    = (float*)(ws + 294912);                    // 589824 B
  _Float16* wqF   = (_Float16*)(ws + 294912 + 589824);        // 294912 B
  float*    colsum = (float*)(ws + 294912 + 589824 + 294912); // 9216 B
  const size_t QF_OFF = 1204224;                              // 256B-aligned
  const size_t QF_BYTES = (size_t)BB * NBTOT * 4 * 512 * 2;   // 18.87 MB
  _Float16* qF = (_Float16*)(ws + QF_OFF);
  float* part = out;  // 1.33 MB scratch inside d_out; dead before attn writes

  pool_kernel<<<(2 * BB * CC * MP) / 256, 256, 0, stream>>>(K, V, kptF, vp);
  if (ws_size >= QF_OFF + QF_BYTES) {
    qprep_kernel<<<(BB * NBTOT * 4 * 64) / 256, 256, 0, stream>>>(Q, qF);
    colsum_qf_kernel<<<(BB * NCHUNK * 9) / 8, 512, 0, stream>>>(qF, kptF, part);
    colsum_reduce_kernel<<<(BB * MP) / 256, 256, 0, stream>>>(part, colsum);
    wprep_kernel<<<(BB * CC * MP) / 256, 256, 0, stream>>>(vp, colsum, wqF);
    attn_qf_kernel<<<dim3(NBTOT / 4, BB), 256, 0, stream>>>(qF, kptF, wqF, out);
  } else {
    colsum_fb_kernel<<<dim3(NCHUNK, BB), 576, 0, stream>>>(Q, kptF, part);
    colsum_reduce_kernel<<<(BB * MP) / 256, 256, 0, stream>>>(part, colsum);
    wprep_kernel<<<(BB * CC * MP) / 256, 256, 0, stream>>>(vp, colsum, wqF);
    attn_main_kernel<<<dim3(HWN / 128, BB), 256, 0, stream>>>(Q, kptF, wqF, out);
  }
}